// Round 4
// baseline (88.344 us; speedup 1.0000x reference)
//
#include <hip/hip_runtime.h>
#include <hip/hip_cooperative_groups.h>
#include <math.h>

// Problem constants (from setup_inputs): B=4, C=4, H=96, W=96
#define BB 4
#define CC 4
#define HH 96
#define WW 96
#define NN (HH * WW)
#define WPR (WW / 4)          // 24 u32 words per row
#define NW (NN / 4)           // 2304 words per image
#define BIGF 1e10f
#define QROWS (HH / 4)        // 24 rows per block quarter

// ---------------------------------------------------------------------------
// Single cooperative kernel. One block per (batch b, direction e, quarter q),
// blk = b*8 + e*4 + q.
//   e=0: EDT of maskP, masked max over maskT pixels (bwd)
//   e=1: EDT of maskT, masked max over maskP pixels (fwd)
// Grid-wide sync, then block 0 folds 32 partials into the scalar output.
// ---------------------------------------------------------------------------
__global__ __launch_bounds__(1024) void k_all(const float* __restrict__ out,
                                              const int* __restrict__ tgt,
                                              float* __restrict__ partial,
                                              float* __restrict__ outv) {
    // LDS carve, 64,512 B total. Region A (36864 B) is time-shared:
    //   P1/P2: predL (9216) + tgtL (9216);  P3b/P4: gq (full 36864, fp32 EDT)
    __shared__ __align__(16) unsigned char smem[64512];
    unsigned char* predL  = smem;                          //  9216 B (dead after P2)
    unsigned char* tgtL   = smem + 9216;                   //  9216 B (dead after P2)
    float* gq             = (float*)smem;                  // 36864 B (live from P3b)
    unsigned char* maskE  = smem + 36864;                  //  9216 B
    unsigned char* maskO  = smem + 46080;                  //  9216 B
    unsigned int* colbits = (unsigned int*)(smem + 55296); //  1920 B (stride 5)
    float* red            = (float*)(smem + 57216);        //    64 B

    const int blk = blockIdx.x;
    const int q = blk & 3;
    const int e = (blk >> 2) & 1;
    const int b = blk >> 3;
    const int tid = threadIdx.x;

    // ---- P1: argmax over C (strict >, first-max) + pack tgt to u8. 4 px/thread ----
    const float* obase = out + (size_t)b * CC * NN;
    const int* tbase = tgt + b * NN;
    for (int w = tid; w < NW; w += 1024) {
        int p = w * 4;
        float4 c0 = *(const float4*)(obase + p);
        float4 c1 = *(const float4*)(obase + NN + p);
        float4 c2 = *(const float4*)(obase + 2 * NN + p);
        float4 c3 = *(const float4*)(obase + 3 * NN + p);
        unsigned int pk = 0;
        {
            float bv = c0.x; int bc = 0;
            if (c1.x > bv) { bv = c1.x; bc = 1; }
            if (c2.x > bv) { bv = c2.x; bc = 2; }
            if (c3.x > bv) { bv = c3.x; bc = 3; }
            pk |= (unsigned int)bc;
        }
        {
            float bv = c0.y; int bc = 0;
            if (c1.y > bv) { bv = c1.y; bc = 1; }
            if (c2.y > bv) { bv = c2.y; bc = 2; }
            if (c3.y > bv) { bv = c3.y; bc = 3; }
            pk |= (unsigned int)bc << 8;
        }
        {
            float bv = c0.z; int bc = 0;
            if (c1.z > bv) { bv = c1.z; bc = 1; }
            if (c2.z > bv) { bv = c2.z; bc = 2; }
            if (c3.z > bv) { bv = c3.z; bc = 3; }
            pk |= (unsigned int)bc << 16;
        }
        {
            float bv = c0.w; int bc = 0;
            if (c1.w > bv) { bv = c1.w; bc = 1; }
            if (c2.w > bv) { bv = c2.w; bc = 2; }
            if (c3.w > bv) { bv = c3.w; bc = 3; }
            pk |= (unsigned int)bc << 24;
        }
        ((unsigned int*)predL)[w] = pk;
        int4 tv = *(const int4*)(tbase + p);
        ((unsigned int*)tgtL)[w] =
            (tv.x & 0xFF) | ((tv.y & 0xFF) << 8) | ((tv.z & 0xFF) << 16) | ((tv.w & 0xFF) << 24);
    }
    __syncthreads();

    // ---- P2: boundary masks, word-parallel (4 px/thread) ----
    const unsigned int* pw = (const unsigned int*)predL;
    const unsigned int* tw = (const unsigned int*)tgtL;
    for (int w = tid; w < NW; w += 1024) {
        int i = w / WPR;
        int jw = w - i * WPR;
        unsigned int mP, mT;
        #pragma unroll
        for (int s = 0; s < 2; ++s) {
            const unsigned int* src = s ? tw : pw;
            unsigned int c = src[w];
            unsigned int diff = 0;
            if (i > 0)      diff |= c ^ src[w - WPR];
            if (i < HH - 1) diff |= c ^ src[w + WPR];
            unsigned int l = (c << 8) | (jw > 0 ? (src[w - 1] >> 24) : (c & 0xFFu));
            diff |= c ^ l;
            unsigned int r = (c >> 8) | (jw < WPR - 1 ? (src[w + 1] << 24) : (c & 0xFF000000u));
            diff |= c ^ r;
            // per-byte nonzero -> 0x01
            unsigned int y = (((diff & 0x7F7F7F7Fu) + 0x7F7F7F7Fu) | diff) & 0x80808080u;
            unsigned int m01 = (y >> 7);
            if (s) mT = m01; else mP = m01;
        }
        ((unsigned int*)maskE)[w] = e ? mT : mP;
        ((unsigned int*)maskO)[w] = e ? mP : mT;
    }
    __syncthreads();   // maskE/maskO ready; predL/tgtL dead from here

    // ---- P3a: pack columns of maskE into bitmasks (3 u32 words / column) ----
    if (tid < 96 * 3) {
        int j = tid / 3, w = tid - j * 3;
        const unsigned char* colp = &maskE[w * 32 * WW + j];
        unsigned int bits = 0;
        #pragma unroll
        for (int r = 0; r < 32; ++r) bits |= ((unsigned int)colp[r * WW]) << r;
        colbits[j * 5 + w] = bits;
    }
    __syncthreads();

    // ---- P3b: column EDT, O(1)/pixel via clz/ffs on the column bitmask ----
    for (int p = tid; p < NN; p += 1024) {
        int i = p / WW;
        int j = p - i * WW;
        unsigned int w0 = colbits[j * 5 + 0];
        unsigned int w1 = colbits[j * 5 + 1];
        unsigned int hi = colbits[j * 5 + 2];
        unsigned long long lo = (unsigned long long)w0 | ((unsigned long long)w1 << 32);
        int up = 1 << 20, dn = 1 << 20;
        if (i < 64) {
            unsigned long long mu = lo & (~0ull >> (63 - i));          // rows 0..i
            if (mu) up = i - (63 - __clzll(mu));
            unsigned long long md = lo >> i;                           // rows i..63
            if (md) dn = __ffsll(md) - 1;
            else if (hi) dn = (64 - i) + (__ffs(hi) - 1);
        } else {
            int ih = i - 64;
            unsigned int mu = hi & (0xFFFFFFFFu >> (31 - ih));         // rows 64..i
            if (mu) up = ih - (31 - __clz(mu));
            else if (lo) up = i - (63 - __clzll(lo));
            unsigned int md = hi >> ih;                                // rows i..95
            if (md) dn = __ffs(md) - 1;
        }
        int d = (up < dn) ? up : dn;
        gq[p] = (d < HH) ? (float)(d * d) : BIGF;
    }
    __syncthreads();

    // ---- P4: row pass (exact sq. EDT) fused with masked max over maskO ----
    float m = -BIGF;
    const int pix0 = q * QROWS * WW;          // this block's 2304 pixels
    for (int p4 = tid; p4 < QROWS * WW; p4 += 1024) {
        int p = pix0 + p4;
        int i = p / WW;
        int j = p - i * WW;
        const float* grow = &gq[i * WW];
        float best = BIGF;
        float d0 = (float)j;                   // j - jp, jp starts at 0
        #pragma unroll 6
        for (int jp = 0; jp < WW; jp += 4) {
            float4 gv = *(const float4*)(grow + jp);   // wave-uniform addr: broadcast
            float a0 = d0;        best = fminf(best, fmaf(a0, a0, gv.x));
            float a1 = d0 - 1.f;  best = fminf(best, fmaf(a1, a1, gv.y));
            float a2 = d0 - 2.f;  best = fminf(best, fmaf(a2, a2, gv.z));
            float a3 = d0 - 3.f;  best = fminf(best, fmaf(a3, a3, gv.w));
            d0 -= 4.0f;
        }
        if (maskO[p]) m = fmaxf(m, best);
    }
    // block max-reduce (16 waves)
    #pragma unroll
    for (int off = 32; off > 0; off >>= 1) m = fmaxf(m, __shfl_down(m, off));
    const int wid = tid >> 6, lid = tid & 63;
    if (lid == 0) red[wid] = m;
    __syncthreads();
    if (tid == 0) {
        float mm = red[0];
        #pragma unroll
        for (int w = 1; w < 16; ++w) mm = fmaxf(mm, red[w]);
        partial[blk] = mm;
        __threadfence();   // make partial visible device-wide before grid sync
    }

    // ---- grid-wide sync, then block 0 finalizes ----
    cooperative_groups::this_grid().sync();
    if (blk == 0 && tid == 0) {
        float s = 0.0f;
        #pragma unroll
        for (int bb = 0; bb < BB; ++bb) {
            float bwd = -BIGF, fwd = -BIGF;
            #pragma unroll
            for (int qq = 0; qq < 4; ++qq) {
                bwd = fmaxf(bwd, partial[bb * 8 + qq]);       // e=0 quarters
                fwd = fmaxf(fwd, partial[bb * 8 + 4 + qq]);   // e=1 quarters
            }
            s += sqrtf(fmaxf(fmaxf(fwd, bwd), 0.0f));
        }
        outv[0] = s * 0.25f;
    }
}

// ---------------------------------------------------------------------------
extern "C" void kernel_launch(void* const* d_in, const int* in_sizes, int n_in,
                              void* d_out, int out_size, void* d_ws, size_t ws_size,
                              hipStream_t stream) {
    const float* output = (const float*)d_in[0];   // [B,C,H,W] fp32
    const int* target   = (const int*)d_in[1];     // [B,H,W] int32
    float* outv         = (float*)d_out;           // scalar fp32
    float* partial      = (float*)d_ws;            // 32 floats

    void* args[] = { (void*)&output, (void*)&target, (void*)&partial, (void*)&outv };
    hipLaunchCooperativeKernel((const void*)k_all, dim3(32), dim3(1024), args, 0, stream);
}

// Round 5
// 64.707 us; speedup vs baseline: 1.3653x; 1.3653x over previous
//
#include <hip/hip_runtime.h>
#include <math.h>

// Problem constants (from setup_inputs): B=4, C=4, H=96, W=96
#define BB 4
#define CC 4
#define HH 96
#define WW 96
#define NN (HH * WW)
#define WPR (WW / 4)          // 24 u32 words per row
#define NW (NN / 4)           // 2304 words per image
#define BIGF 1e10f
#define QROWS (HH / 4)        // 24 rows per block quarter

// ---------------------------------------------------------------------------
// K1: one block per (batch b, direction e, quarter q). blk = b*8 + e*4 + q
//   e=0: EDT of maskP, masked max over maskT pixels (bwd)
//   e=1: EDT of maskT, masked max over maskP pixels (fwd)
// All intermediates in LDS. Vectorized prep (float4/int4 loads, word-parallel
// boundary masks), column EDT via per-column 96-bit masks + clz/ffs.
// Writes one partial max per block. Ordinary launch — cooperative launch
// measured +13 µs overhead (R4), reverted.
// ---------------------------------------------------------------------------
__global__ __launch_bounds__(1024) void k_fused(const float* __restrict__ out,
                                                const int* __restrict__ tgt,
                                                float* __restrict__ partial) {
    // LDS carve, 64,512 B total. Region A (36864 B) is time-shared:
    //   P1/P2: predL (9216) + tgtL (9216);  P3b/P4: gq (full 36864, fp32 EDT)
    __shared__ __align__(16) unsigned char smem[64512];
    unsigned char* predL  = smem;                          //  9216 B (dead after P2)
    unsigned char* tgtL   = smem + 9216;                   //  9216 B (dead after P2)
    float* gq             = (float*)smem;                  // 36864 B (live from P3b)
    unsigned char* maskE  = smem + 36864;                  //  9216 B
    unsigned char* maskO  = smem + 46080;                  //  9216 B
    unsigned int* colbits = (unsigned int*)(smem + 55296); //  1920 B (stride 5)
    float* red            = (float*)(smem + 57216);        //    64 B

    const int blk = blockIdx.x;
    const int q = blk & 3;
    const int e = (blk >> 2) & 1;
    const int b = blk >> 3;
    const int tid = threadIdx.x;

    // ---- P1: argmax over C (strict >, first-max) + pack tgt to u8. 4 px/thread ----
    const float* obase = out + (size_t)b * CC * NN;
    const int* tbase = tgt + b * NN;
    for (int w = tid; w < NW; w += 1024) {
        int p = w * 4;
        float4 c0 = *(const float4*)(obase + p);
        float4 c1 = *(const float4*)(obase + NN + p);
        float4 c2 = *(const float4*)(obase + 2 * NN + p);
        float4 c3 = *(const float4*)(obase + 3 * NN + p);
        unsigned int pk = 0;
        {
            float bv = c0.x; int bc = 0;
            if (c1.x > bv) { bv = c1.x; bc = 1; }
            if (c2.x > bv) { bv = c2.x; bc = 2; }
            if (c3.x > bv) { bv = c3.x; bc = 3; }
            pk |= (unsigned int)bc;
        }
        {
            float bv = c0.y; int bc = 0;
            if (c1.y > bv) { bv = c1.y; bc = 1; }
            if (c2.y > bv) { bv = c2.y; bc = 2; }
            if (c3.y > bv) { bv = c3.y; bc = 3; }
            pk |= (unsigned int)bc << 8;
        }
        {
            float bv = c0.z; int bc = 0;
            if (c1.z > bv) { bv = c1.z; bc = 1; }
            if (c2.z > bv) { bv = c2.z; bc = 2; }
            if (c3.z > bv) { bv = c3.z; bc = 3; }
            pk |= (unsigned int)bc << 16;
        }
        {
            float bv = c0.w; int bc = 0;
            if (c1.w > bv) { bv = c1.w; bc = 1; }
            if (c2.w > bv) { bv = c2.w; bc = 2; }
            if (c3.w > bv) { bv = c3.w; bc = 3; }
            pk |= (unsigned int)bc << 24;
        }
        ((unsigned int*)predL)[w] = pk;
        int4 tv = *(const int4*)(tbase + p);
        ((unsigned int*)tgtL)[w] =
            (tv.x & 0xFF) | ((tv.y & 0xFF) << 8) | ((tv.z & 0xFF) << 16) | ((tv.w & 0xFF) << 24);
    }
    __syncthreads();

    // ---- P2: boundary masks, word-parallel (4 px/thread) ----
    const unsigned int* pw = (const unsigned int*)predL;
    const unsigned int* tw = (const unsigned int*)tgtL;
    for (int w = tid; w < NW; w += 1024) {
        int i = w / WPR;
        int jw = w - i * WPR;
        unsigned int mP, mT;
        #pragma unroll
        for (int s = 0; s < 2; ++s) {
            const unsigned int* src = s ? tw : pw;
            unsigned int c = src[w];
            unsigned int diff = 0;
            if (i > 0)      diff |= c ^ src[w - WPR];
            if (i < HH - 1) diff |= c ^ src[w + WPR];
            unsigned int l = (c << 8) | (jw > 0 ? (src[w - 1] >> 24) : (c & 0xFFu));
            diff |= c ^ l;
            unsigned int r = (c >> 8) | (jw < WPR - 1 ? (src[w + 1] << 24) : (c & 0xFF000000u));
            diff |= c ^ r;
            // per-byte nonzero -> 0x01
            unsigned int y = (((diff & 0x7F7F7F7Fu) + 0x7F7F7F7Fu) | diff) & 0x80808080u;
            unsigned int m01 = (y >> 7);
            if (s) mT = m01; else mP = m01;
        }
        ((unsigned int*)maskE)[w] = e ? mT : mP;
        ((unsigned int*)maskO)[w] = e ? mP : mT;
    }
    __syncthreads();   // maskE/maskO ready; predL/tgtL dead from here

    // ---- P3a: pack columns of maskE into bitmasks (3 u32 words / column) ----
    if (tid < 96 * 3) {
        int j = tid / 3, w = tid - j * 3;
        const unsigned char* colp = &maskE[w * 32 * WW + j];
        unsigned int bits = 0;
        #pragma unroll
        for (int r = 0; r < 32; ++r) bits |= ((unsigned int)colp[r * WW]) << r;
        colbits[j * 5 + w] = bits;
    }
    __syncthreads();

    // ---- P3b: column EDT, O(1)/pixel via clz/ffs on the column bitmask ----
    for (int p = tid; p < NN; p += 1024) {
        int i = p / WW;
        int j = p - i * WW;
        unsigned int w0 = colbits[j * 5 + 0];
        unsigned int w1 = colbits[j * 5 + 1];
        unsigned int hi = colbits[j * 5 + 2];
        unsigned long long lo = (unsigned long long)w0 | ((unsigned long long)w1 << 32);
        int up = 1 << 20, dn = 1 << 20;
        if (i < 64) {
            unsigned long long mu = lo & (~0ull >> (63 - i));          // rows 0..i
            if (mu) up = i - (63 - __clzll(mu));
            unsigned long long md = lo >> i;                           // rows i..63
            if (md) dn = __ffsll(md) - 1;
            else if (hi) dn = (64 - i) + (__ffs(hi) - 1);
        } else {
            int ih = i - 64;
            unsigned int mu = hi & (0xFFFFFFFFu >> (31 - ih));         // rows 64..i
            if (mu) up = ih - (31 - __clz(mu));
            else if (lo) up = i - (63 - __clzll(lo));
            unsigned int md = hi >> ih;                                // rows i..95
            if (md) dn = __ffs(md) - 1;
        }
        int d = (up < dn) ? up : dn;
        gq[p] = (d < HH) ? (float)(d * d) : BIGF;
    }
    __syncthreads();

    // ---- P4: row pass (exact sq. EDT) fused with masked max over maskO ----
    float m = -BIGF;
    const int pix0 = q * QROWS * WW;          // this block's 2304 pixels
    for (int p4 = tid; p4 < QROWS * WW; p4 += 1024) {
        int p = pix0 + p4;
        int i = p / WW;
        int j = p - i * WW;
        const float* grow = &gq[i * WW];
        float best = BIGF;
        float d0 = (float)j;                   // j - jp, jp starts at 0
        #pragma unroll 6
        for (int jp = 0; jp < WW; jp += 4) {
            float4 gv = *(const float4*)(grow + jp);   // wave-uniform addr: broadcast
            float a0 = d0;        best = fminf(best, fmaf(a0, a0, gv.x));
            float a1 = d0 - 1.f;  best = fminf(best, fmaf(a1, a1, gv.y));
            float a2 = d0 - 2.f;  best = fminf(best, fmaf(a2, a2, gv.z));
            float a3 = d0 - 3.f;  best = fminf(best, fmaf(a3, a3, gv.w));
            d0 -= 4.0f;
        }
        if (maskO[p]) m = fmaxf(m, best);
    }
    // block max-reduce (16 waves)
    #pragma unroll
    for (int off = 32; off > 0; off >>= 1) m = fmaxf(m, __shfl_down(m, off));
    const int wid = tid >> 6, lid = tid & 63;
    if (lid == 0) red[wid] = m;
    __syncthreads();
    if (tid == 0) {
        float mm = red[0];
        #pragma unroll
        for (int w = 1; w < 16; ++w) mm = fmaxf(mm, red[w]);
        partial[blk] = mm;
    }
}

// ---------------------------------------------------------------------------
// K2: combine 32 partials -> mean over batches of sqrt(max(fwd,bwd,0))
// ---------------------------------------------------------------------------
__global__ void k_fin(const float* __restrict__ partial, float* __restrict__ outv) {
    if (threadIdx.x == 0) {
        float s = 0.0f;
        #pragma unroll
        for (int b = 0; b < BB; ++b) {
            float bwd = -BIGF, fwd = -BIGF;
            #pragma unroll
            for (int qq = 0; qq < 4; ++qq) {
                bwd = fmaxf(bwd, partial[b * 8 + qq]);       // e=0 quarters
                fwd = fmaxf(fwd, partial[b * 8 + 4 + qq]);   // e=1 quarters
            }
            s += sqrtf(fmaxf(fmaxf(fwd, bwd), 0.0f));
        }
        outv[0] = s * 0.25f;
    }
}

// ---------------------------------------------------------------------------
extern "C" void kernel_launch(void* const* d_in, const int* in_sizes, int n_in,
                              void* d_out, int out_size, void* d_ws, size_t ws_size,
                              hipStream_t stream) {
    const float* output = (const float*)d_in[0];   // [B,C,H,W] fp32
    const int* target   = (const int*)d_in[1];     // [B,H,W] int32
    float* outv         = (float*)d_out;           // scalar fp32
    float* partial      = (float*)d_ws;            // 32 floats

    k_fused<<<32, 1024, 0, stream>>>(output, target, partial);
    k_fin<<<1, 64, 0, stream>>>(partial, outv);
}